// Round 10
// baseline (2391.704 us; speedup 1.0000x reference)
//
#include <hip/hip_runtime.h>
#include <hip/hip_fp16.h>
#include <math.h>

#define B_ 64
#define N_ 512
#define H_ 32
#define E_ 4
#define NSTEPS 5
#define KTOT 2048       // N_*E_

typedef _Float16 half8 __attribute__((ext_vector_type(8)));
typedef float   f32x4 __attribute__((ext_vector_type(4)));

// async global->LDS, 16B per lane, dest = wave-uniform base + lane*16
__device__ __forceinline__ void gld16(const void* g, void* l) {
    __builtin_amdgcn_global_load_lds(
        (const __attribute__((address_space(1))) void*)g,
        (__attribute__((address_space(3))) void*)l, 16, 0, 0);
}

// ---------------------------------------------------------------- s projection
// hsrc = x on step 0, h afterwards (k_init_h eliminated)
__global__ __launch_bounds__(256) void k_s(const float* __restrict__ hsrc,
                                           const float* __restrict__ W_in,
                                           const float* __restrict__ b_in,
                                           const float* __restrict__ W_out,
                                           const float* __restrict__ b_out,
                                           _Float16* __restrict__ sT_in_hi,
                                           _Float16* __restrict__ sT_in_lo,
                                           _Float16* __restrict__ sT_out_hi,
                                           _Float16* __restrict__ sT_out_lo) {
    int b  = blockIdx.x >> 3;
    int n0 = (blockIdx.x & 7) * 64;
    int lane = threadIdx.x & 63;
    int w = __builtin_amdgcn_readfirstlane((int)(threadIdx.x >> 6)); // 0..3
    int n = n0 + lane;

    const float* hrow = hsrc + ((size_t)b * N_ + n) * H_;
    f32x4 hv[8];
#pragma unroll
    for (int c = 0; c < 8; c++) hv[c] = ((const f32x4*)hrow)[c];

#pragma unroll 4
    for (int o = 0; o < 32; o++) {
        int he = w * 32 + o;
        const f32x4* wr = (const f32x4*)(W_in + (size_t)he * H_);
        float acc = b_in[he];
#pragma unroll
        for (int c = 0; c < 8; c++) {
            f32x4 wv = wr[c];
            acc += hv[c][0]*wv[0] + hv[c][1]*wv[1] + hv[c][2]*wv[2] + hv[c][3]*wv[3];
        }
        int hh = he >> 2, e = he & 3;
        size_t idx = ((size_t)b * H_ + hh) * KTOT + e * N_ + n;
        _Float16 hi = (_Float16)acc;
        sT_in_hi[idx] = hi;
        sT_in_lo[idx] = (_Float16)(acc - (float)hi);
    }
#pragma unroll 4
    for (int o = 0; o < 32; o++) {
        int he = w * 32 + o;
        const f32x4* wr = (const f32x4*)(W_out + (size_t)he * H_);
        float acc = b_out[he];
#pragma unroll
        for (int c = 0; c < 8; c++) {
            f32x4 wv = wr[c];
            acc += hv[c][0]*wv[0] + hv[c][1]*wv[1] + hv[c][2]*wv[2] + hv[c][3]*wv[3];
        }
        int hh = he >> 2, e = he & 3;
        size_t idx = ((size_t)b * H_ + hh) * KTOT + e * N_ + n;
        _Float16 hi = (_Float16)acc;
        sT_out_hi[idx] = hi;
        sT_out_lo[idx] = (_Float16)(acc - (float)hi);
    }
}

// ---------------------------------------------------------------- fused einsum+gate
// block = (nblk, b): 64 n-rows, BOTH dirs (64 chunks of K=64, pipeline carried
// across the dir boundary), counted-vmcnt 2-deep gld16 staging (round-9 proven),
// a_in/a_out kept in LDS, GRU gate applied inline, h written directly.
// Grid 512 = exactly 2 blocks/CU (all resident, no rounds). LDS ~73 KB.
#define CHB   256     // chunk bytes per m row (64 floats)
#define BUFA2 16384   // 64 rows x 256B
#define BUFSZ 24576   // A(16K) + B(2 planes x 32 rows x 128B = 8K)
__global__ __launch_bounds__(256, 2) void k_fuse(const float* __restrict__ m,
                                                 const _Float16* __restrict__ sT_in_hi,
                                                 const _Float16* __restrict__ sT_in_lo,
                                                 const _Float16* __restrict__ sT_out_hi,
                                                 const _Float16* __restrict__ sT_out_lo,
                                                 const float* __restrict__ hold_src,
                                                 float* __restrict__ hstate,
                                                 const float* __restrict__ Wz,
                                                 const float* __restrict__ bz,
                                                 const float* __restrict__ Wr,
                                                 const float* __restrict__ br,
                                                 const float* __restrict__ Wt,
                                                 const float* __restrict__ bt) {
    __shared__ __align__(16) char lds[2 * BUFSZ];   // 48 KB staging
    __shared__ float aBuf[64][96];                  // 24 KB: a_in|a_out|hold
    __shared__ float rhL[8][32];
    int bid  = blockIdx.x;                 // 0..511
    int xcd  = bid & 7, loc = bid >> 3;    // keep one b's 8 blocks on one XCD
    int b    = xcd * 8 + (loc >> 3);
    int nblk = loc & 7;
    int n0   = nblk * 64;
    int tid  = threadIdx.x;
    int w    = tid >> 6;
    int lane = tid & 63;
    int l15  = lane & 15;
    int quad = lane >> 4;

    const char* mBase = (const char*)(m + ((size_t)(b * N_ + n0)) * (2 * KTOT));
    const float* hold = hold_src + ((size_t)b * N_ + n0) * H_;

    // stage hold rows into aBuf cols 64..95 (disjoint from staging bufs)
    for (int i = tid; i < 2048; i += 256)
        aBuf[i >> 5][64 + (i & 31)] = hold[((i >> 5) * 32) + (i & 31)];

    // per-wave staging roles
    int bp   = w >> 1;                 // B plane (0=hi,1=lo)
    int brb  = (w & 1) << 4;           // B row base (0 or 16)
    const char* sHiD[2] = { (const char*)(sT_in_hi  + (size_t)b * H_ * KTOT),
                            (const char*)(sT_out_hi + (size_t)b * H_ * KTOT) };
    const char* sLoD[2] = { (const char*)(sT_in_lo  + (size_t)b * H_ * KTOT),
                            (const char*)(sT_out_lo + (size_t)b * H_ * KTOT) };

    // stage flat-chunk cc (= dir*32 + c) into buffer buf: 6 gld16 per wave
    auto STAGE = [&](int cc, int buf) {
        int dir_s = cc >> 5, c = cc & 31;
        char* dA = lds + buf * BUFSZ;
        char* dB = lds + buf * BUFSZ + BUFA2 + bp * 4096;
        const char* mD = mBase + dir_s * 8192;
        const char* sP = bp ? sLoD[dir_s] : sHiD[dir_s];
#pragma unroll
        for (int i = 0; i < 4; i++) {                 // A: 4 rows per instr
            int r = (w << 4) + i * 4 + (lane >> 4);
            const char* g = mD + (size_t)r * (2 * KTOT * 4) + c * CHB
                            + (((lane & 15) * 16) ^ ((r & 7) << 4));
            gld16(g, dA + ((w << 4) + i * 4) * 256);
        }
#pragma unroll
        for (int i = 0; i < 2; i++) {                 // B: 8 rows per instr
            int r = brb + i * 8 + (lane >> 3);
            const char* g = sP + (size_t)r * (KTOT * 2) + c * 128
                            + (((lane & 7) * 16) ^ ((r & 7) << 4));
            gld16(g, dB + (brb + i * 8) * 128);
        }
    };

    f32x4 acc0 = {0.f,0.f,0.f,0.f}, acc1 = {0.f,0.f,0.f,0.f};

    int rowA  = (w << 4) + l15;
    int swzA  = (rowA & 7) << 4;
    int swzB0 = (l15 & 7) << 4;        // rows l15 and l15+16 share row&7

    STAGE(0, 0);

    for (int cc = 0; cc < 64; cc++) {
        int buf = cc & 1;
        if (cc < 63) STAGE(cc + 1, buf ^ 1);
        if (cc < 63) asm volatile("s_waitcnt vmcnt(6)" ::: "memory");
        else         asm volatile("s_waitcnt vmcnt(0)" ::: "memory");
        __builtin_amdgcn_s_barrier();
        __builtin_amdgcn_sched_barrier(0);

        const char* Ab = lds + buf * BUFSZ + rowA * 256;
        const char* Bh = lds + buf * BUFSZ + BUFA2;
        const char* Bl = Bh + 4096;
#pragma unroll
        for (int it = 0; it < 2; it++) {
            int kab = it * 128 + quad * 32;          // A byte offset in row
            f32x4 a0 = *(const f32x4*)(Ab + (kab ^ swzA));
            f32x4 a1 = *(const f32x4*)(Ab + ((kab + 16) ^ swzA));

            int kbb = it * 64 + quad * 16;           // B byte offset in row
            int o0 = l15 * 128        + (kbb ^ swzB0);
            int o1 = (l15 + 16) * 128 + (kbb ^ swzB0);
            half8 Bhi0 = *(const half8*)(Bh + o0);
            half8 Bhi1 = *(const half8*)(Bh + o1);
            half8 Blo0 = *(const half8*)(Bl + o0);
            half8 Blo1 = *(const half8*)(Bl + o1);

            half8 Ahi, Alo;
#pragma unroll
            for (int j = 0; j < 4; j++) {
                float v0 = a0[j], v1 = a1[j];
                _Float16 h0 = (_Float16)v0, h1 = (_Float16)v1;
                Ahi[j]     = h0;
                Ahi[j + 4] = h1;
                Alo[j]     = (_Float16)(v0 - (float)h0);
                Alo[j + 4] = (_Float16)(v1 - (float)h1);
            }
            acc0 = __builtin_amdgcn_mfma_f32_16x16x32_f16(Ahi, Bhi0, acc0, 0, 0, 0);
            acc1 = __builtin_amdgcn_mfma_f32_16x16x32_f16(Ahi, Bhi1, acc1, 0, 0, 0);
            acc0 = __builtin_amdgcn_mfma_f32_16x16x32_f16(Ahi, Blo0, acc0, 0, 0, 0);
            acc1 = __builtin_amdgcn_mfma_f32_16x16x32_f16(Ahi, Blo1, acc1, 0, 0, 0);
            acc0 = __builtin_amdgcn_mfma_f32_16x16x32_f16(Alo, Bhi0, acc0, 0, 0, 0);
            acc1 = __builtin_amdgcn_mfma_f32_16x16x32_f16(Alo, Bhi1, acc1, 0, 0, 0);
        }
        if (cc == 31) {                 // dir 0 done: stash a_in, reset acc
            int row = (w << 4) + (quad << 2);
#pragma unroll
            for (int r = 0; r < 4; r++) {
                aBuf[row + r][l15]      = acc0[r];
                aBuf[row + r][16 + l15] = acc1[r];
            }
            acc0 = (f32x4){0.f,0.f,0.f,0.f};
            acc1 = (f32x4){0.f,0.f,0.f,0.f};
        }
        __builtin_amdgcn_sched_barrier(0);
        __builtin_amdgcn_s_barrier();   // all waves done reading buf
    }
    {   // dir 1: stash a_out
        int row = (w << 4) + (quad << 2);
#pragma unroll
        for (int r = 0; r < 4; r++) {
            aBuf[row + r][32 + l15] = acc0[r];
            aBuf[row + r][48 + l15] = acc1[r];
        }
    }
    __syncthreads();

    // ---------------- GRU gate inline: 8 passes of 8 rows
    int rg = tid >> 5, ig = tid & 31;
    for (int ps = 0; ps < 8; ps++) {
        int row = ps * 8 + rg;
        float az = bz[ig], ar = br[ig];
        const f32x4* wzr = (const f32x4*)(Wz + (size_t)ig * 96);
        const f32x4* wrr = (const f32x4*)(Wr + (size_t)ig * 96);
        const f32x4* crow = (const f32x4*)aBuf[row];
#pragma unroll
        for (int kc = 0; kc < 24; kc++) {
            f32x4 cv = crow[kc];
            f32x4 wz = wzr[kc];
            f32x4 wr = wrr[kc];
            az += cv[0]*wz[0] + cv[1]*wz[1] + cv[2]*wz[2] + cv[3]*wz[3];
            ar += cv[0]*wr[0] + cv[1]*wr[1] + cv[2]*wr[2] + cv[3]*wr[3];
        }
        float z  = 1.f / (1.f + __expf(-az));
        float rgt = 1.f / (1.f + __expf(-ar));
        float holdv = aBuf[row][64 + ig];
        rhL[rg][ig] = rgt * holdv;
        __syncthreads();

        float at = bt[ig];
        const f32x4* wtr = (const f32x4*)(Wt + (size_t)ig * 96);
#pragma unroll
        for (int kc = 0; kc < 16; kc++) {
            f32x4 cv = crow[kc];
            f32x4 wt = wtr[kc];
            at += cv[0]*wt[0] + cv[1]*wt[1] + cv[2]*wt[2] + cv[3]*wt[3];
        }
        const f32x4* rrow = (const f32x4*)rhL[rg];
#pragma unroll
        for (int kc = 0; kc < 8; kc++) {
            f32x4 cv = rrow[kc];
            f32x4 wt = wtr[16 + kc];
            at += cv[0]*wt[0] + cv[1]*wt[1] + cv[2]*wt[2] + cv[3]*wt[3];
        }
        float hh = tanhf(at);
        hstate[((size_t)b * N_ + n0 + row) * H_ + ig] = (1.f - z) * holdv + z * hh;
        __syncthreads();   // rhL reuse next pass
    }
}

// ---------------------------------------------------------------- readout
__global__ __launch_bounds__(256) void k_final(const float* __restrict__ hstate,
                                               const float* __restrict__ a,
                                               const float* __restrict__ W1,
                                               const float* __restrict__ b1,
                                               const float* __restrict__ W2,
                                               const float* __restrict__ b2,
                                               float* __restrict__ out) {
    __shared__ float hl[8][32];
    __shared__ float as[8];
    int base = blockIdx.x * 8;
    int t = threadIdx.x;
    {
        int r = t >> 5, c = t & 31;
        hl[r][c] = hstate[(size_t)(base + r) * 32 + c];
        if (t < 8) as[t] = a[base + t];
    }
    __syncthreads();
    int r = t >> 5, j = t & 31;
    float acc = b1[j];
    const float* w1r = W1 + (size_t)j * 33;
#pragma unroll
    for (int i2 = 0; i2 < 32; i2++) acc += hl[r][i2] * w1r[i2];
    acc += as[r] * w1r[32];
    float o = tanhf(acc) * W2[j];
#pragma unroll
    for (int off = 16; off; off >>= 1) o += __shfl_xor(o, off, 32);
    if (j == 0) out[base + r] = o + b2[0];
}

// ---------------------------------------------------------------- launcher
extern "C" void kernel_launch(void* const* d_in, const int* in_sizes, int n_in,
                              void* d_out, int out_size, void* d_ws, size_t ws_size,
                              hipStream_t stream) {
    const float* x     = (const float*)d_in[0];
    const float* a     = (const float*)d_in[1];
    const float* m     = (const float*)d_in[2];
    const float* W_in  = (const float*)d_in[3];
    const float* b_in  = (const float*)d_in[4];
    const float* W_out = (const float*)d_in[5];
    const float* b_out = (const float*)d_in[6];
    const float* Wz    = (const float*)d_in[7];
    const float* bz    = (const float*)d_in[8];
    const float* Wr    = (const float*)d_in[9];
    const float* br    = (const float*)d_in[10];
    const float* Wt    = (const float*)d_in[11];
    const float* bt    = (const float*)d_in[12];
    const float* W1    = (const float*)d_in[13];
    const float* b1    = (const float*)d_in[14];
    const float* W2    = (const float*)d_in[15];
    const float* b2    = (const float*)d_in[16];
    float* out = (float*)d_out;

    char* ws = (char*)d_ws;
    float*    h         = (float*)(ws);                           // 4 MB
    _Float16* sT_in_hi  = (_Float16*)(ws + ((size_t)4  << 20));   // 8 MB
    _Float16* sT_in_lo  = (_Float16*)(ws + ((size_t)12 << 20));   // 8 MB
    _Float16* sT_out_hi = (_Float16*)(ws + ((size_t)20 << 20));   // 8 MB
    _Float16* sT_out_lo = (_Float16*)(ws + ((size_t)28 << 20));   // 8 MB (36 MB)

    for (int s = 0; s < NSTEPS; s++) {
        const float* hsrc = (s == 0) ? x : h;
        k_s<<<512, 256, 0, stream>>>(hsrc, W_in, b_in, W_out, b_out,
                                     sT_in_hi, sT_in_lo, sT_out_hi, sT_out_lo);
        k_fuse<<<512, 256, 0, stream>>>(m, sT_in_hi, sT_in_lo,
                                        sT_out_hi, sT_out_lo,
                                        hsrc, h, Wz, bz, Wr, br, Wt, bt);
    }
    k_final<<<4096, 256, 0, stream>>>(h, a, W1, b1, W2, b2, out);
}

// Round 11
// 2388.185 us; speedup vs baseline: 1.0015x; 1.0015x over previous
//
#include <hip/hip_runtime.h>
#include <hip/hip_fp16.h>
#include <math.h>

#define B_ 64
#define N_ 512
#define H_ 32
#define E_ 4
#define NSTEPS 5
#define KTOT 2048       // N_*E_

typedef _Float16 half8 __attribute__((ext_vector_type(8)));
typedef float   f32x4 __attribute__((ext_vector_type(4)));

// async global->LDS, 16B per lane; LDS dest = wave-uniform base + lane*16,
// global source is per-lane.
__device__ __forceinline__ void gld16(const void* g, void* l) {
    __builtin_amdgcn_global_load_lds(
        (const __attribute__((address_space(1))) void*)g,
        (__attribute__((address_space(3))) void*)l, 16, 0, 0);
}

// ---------------------------------------------------------------- s projection
// hsrc = x on step 0, h afterwards
__global__ __launch_bounds__(256) void k_s(const float* __restrict__ hsrc,
                                           const float* __restrict__ W_in,
                                           const float* __restrict__ b_in,
                                           const float* __restrict__ W_out,
                                           const float* __restrict__ b_out,
                                           _Float16* __restrict__ sT_in_hi,
                                           _Float16* __restrict__ sT_in_lo,
                                           _Float16* __restrict__ sT_out_hi,
                                           _Float16* __restrict__ sT_out_lo) {
    int b  = blockIdx.x >> 3;
    int n0 = (blockIdx.x & 7) * 64;
    int lane = threadIdx.x & 63;
    int w = __builtin_amdgcn_readfirstlane((int)(threadIdx.x >> 6)); // 0..3
    int n = n0 + lane;

    const float* hrow = hsrc + ((size_t)b * N_ + n) * H_;
    f32x4 hv[8];
#pragma unroll
    for (int c = 0; c < 8; c++) hv[c] = ((const f32x4*)hrow)[c];

#pragma unroll 4
    for (int o = 0; o < 32; o++) {
        int he = w * 32 + o;
        const f32x4* wr = (const f32x4*)(W_in + (size_t)he * H_);
        float acc = b_in[he];
#pragma unroll
        for (int c = 0; c < 8; c++) {
            f32x4 wv = wr[c];
            acc += hv[c][0]*wv[0] + hv[c][1]*wv[1] + hv[c][2]*wv[2] + hv[c][3]*wv[3];
        }
        int hh = he >> 2, e = he & 3;
        size_t idx = ((size_t)b * H_ + hh) * KTOT + e * N_ + n;
        _Float16 hi = (_Float16)acc;
        sT_in_hi[idx] = hi;
        sT_in_lo[idx] = (_Float16)(acc - (float)hi);
    }
#pragma unroll 4
    for (int o = 0; o < 32; o++) {
        int he = w * 32 + o;
        const f32x4* wr = (const f32x4*)(W_out + (size_t)he * H_);
        float acc = b_out[he];
#pragma unroll
        for (int c = 0; c < 8; c++) {
            f32x4 wv = wr[c];
            acc += hv[c][0]*wv[0] + hv[c][1]*wv[1] + hv[c][2]*wv[2] + hv[c][3]*wv[3];
        }
        int hh = he >> 2, e = he & 3;
        size_t idx = ((size_t)b * H_ + hh) * KTOT + e * N_ + n;
        _Float16 hi = (_Float16)acc;
        sT_out_hi[idx] = hi;
        sT_out_lo[idx] = (_Float16)(acc - (float)hi);
    }
}

// ---------------------------------------------------------------- m pre-pack (once)
// pm[tile][c 0..31][r 0..63][256B], tile = (b*2+dir)*8+nblk, XOR-swizzle
// pre-applied: byte (s2*16)^((r&7)<<4). Bit-exact fp32 permutation of m.
// Reads: linear 1KB/wave per row. Writes: 256B granule @16KB stride (via L2).
__global__ __launch_bounds__(256) void k_packm(const float* __restrict__ m,
                                               char* __restrict__ pm) {
    int tile = blockIdx.x;            // 0..1023
    int b = tile >> 4, dir = (tile >> 3) & 1, nblk = tile & 7;
    const char* src = (const char*)m
        + ((size_t)(b * N_ + nblk * 64)) * (2 * KTOT * 4) + dir * (KTOT * 4);
    char* dst = pm + (size_t)tile * 524288;
    int tid = threadIdx.x;
    for (int i = tid; i < 32768; i += 256) {          // 64 rows x 512 segs
        int r = i >> 9, sg = i & 511;
        f32x4 v = *(const f32x4*)(src + (size_t)r * 16384 + sg * 16);
        int c = sg >> 4, s2 = sg & 15;
        *(f32x4*)(dst + (size_t)(c * 64 + r) * 256
                      + ((s2 * 16) ^ ((r & 7) << 4))) = v;
    }
}

// ---------------------------------------------------------------- einsum (packed A)
// block = (nblk, b, dir): 64 n-rows, K=2048 in 32 chunks of 64.
// A staged from pm: ONE linear stream per block, each gld16 = contiguous 1KB.
// B staged from sT as round 9. Counted vmcnt, 2 buffers, 48KB LDS -> 3 blk/CU.
#define BUFA2 16384   // 64 rows x 256B
#define BUFSZ 24576   // A(16K) + B(2 planes x 32 rows x 128B)
__global__ __launch_bounds__(256) void k_einsum_pk(const char* __restrict__ pm,
                                                   const _Float16* __restrict__ sT_in_hi,
                                                   const _Float16* __restrict__ sT_in_lo,
                                                   const _Float16* __restrict__ sT_out_hi,
                                                   const _Float16* __restrict__ sT_out_lo,
                                                   float* __restrict__ a_in,
                                                   float* __restrict__ a_out) {
    __shared__ __align__(16) char lds[2 * BUFSZ];   // 48 KB
    int nblk = blockIdx.x;
    int b    = blockIdx.y;
    int dir  = blockIdx.z;
    int n0   = nblk * 64;
    int tid  = threadIdx.x;
    int w    = tid >> 6;
    int lane = tid & 63;
    int l15  = lane & 15;
    int quad = lane >> 4;

    const char* pmT = pm + (size_t)((b * 2 + dir) * 8 + nblk) * 524288;
    const char* sHi = (const char*)((dir ? sT_out_hi : sT_in_hi) + (size_t)b * H_ * KTOT);
    const char* sLo = (const char*)((dir ? sT_out_lo : sT_in_lo) + (size_t)b * H_ * KTOT);
    float* aout = dir ? a_out : a_in;

    int bp  = w >> 1;                  // B plane (0=hi,1=lo)
    int brb = (w & 1) << 4;            // B row base (0 or 16)
    const char* sP = bp ? sLo : sHi;

    auto STAGE = [&](int c, int buf) {
        char* dA = lds + buf * BUFSZ;
        char* dB = lds + buf * BUFSZ + BUFA2 + bp * 4096;
        const char* gA = pmT + (size_t)c * 16384;
#pragma unroll
        for (int i = 0; i < 4; i++) {                // A: contiguous 1KB/instr
            int off = ((w << 4) + i * 4) * 256;
            gld16(gA + off + lane * 16, dA + off);
        }
#pragma unroll
        for (int i = 0; i < 2; i++) {                // B: 8 rows per instr
            int r = brb + i * 8 + (lane >> 3);
            const char* g = sP + (size_t)r * (KTOT * 2) + c * 128
                            + (((lane & 7) * 16) ^ ((r & 7) << 4));
            gld16(g, dB + (brb + i * 8) * 128);
        }
    };

    f32x4 acc0 = {0.f,0.f,0.f,0.f}, acc1 = {0.f,0.f,0.f,0.f};

    int rowA  = (w << 4) + l15;
    int swzA  = (rowA & 7) << 4;
    int swzB0 = (l15 & 7) << 4;        // rows l15 and l15+16 share row&7

    STAGE(0, 0);

    for (int c = 0; c < 32; c++) {
        int buf = c & 1;
        if (c < 31) STAGE(c + 1, buf ^ 1);
        if (c < 31) asm volatile("s_waitcnt vmcnt(6)" ::: "memory");
        else        asm volatile("s_waitcnt vmcnt(0)" ::: "memory");
        __builtin_amdgcn_s_barrier();
        __builtin_amdgcn_sched_barrier(0);

        const char* Ab = lds + buf * BUFSZ + rowA * 256;
        const char* Bh = lds + buf * BUFSZ + BUFA2;
        const char* Bl = Bh + 4096;
#pragma unroll
        for (int it = 0; it < 2; it++) {
            int kab = it * 128 + quad * 32;          // A byte offset in row
            f32x4 a0 = *(const f32x4*)(Ab + (kab ^ swzA));
            f32x4 a1 = *(const f32x4*)(Ab + ((kab + 16) ^ swzA));

            int kbb = it * 64 + quad * 16;           // B byte offset in row
            int o0 = l15 * 128        + (kbb ^ swzB0);
            int o1 = (l15 + 16) * 128 + (kbb ^ swzB0);
            half8 Bhi0 = *(const half8*)(Bh + o0);
            half8 Bhi1 = *(const half8*)(Bh + o1);
            half8 Blo0 = *(const half8*)(Bl + o0);
            half8 Blo1 = *(const half8*)(Bl + o1);

            half8 Ahi, Alo;
#pragma unroll
            for (int j = 0; j < 4; j++) {
                float v0 = a0[j], v1 = a1[j];
                _Float16 h0 = (_Float16)v0, h1 = (_Float16)v1;
                Ahi[j]     = h0;
                Ahi[j + 4] = h1;
                Alo[j]     = (_Float16)(v0 - (float)h0);
                Alo[j + 4] = (_Float16)(v1 - (float)h1);
            }
            acc0 = __builtin_amdgcn_mfma_f32_16x16x32_f16(Ahi, Bhi0, acc0, 0, 0, 0);
            acc1 = __builtin_amdgcn_mfma_f32_16x16x32_f16(Ahi, Bhi1, acc1, 0, 0, 0);
            acc0 = __builtin_amdgcn_mfma_f32_16x16x32_f16(Ahi, Blo0, acc0, 0, 0, 0);
            acc1 = __builtin_amdgcn_mfma_f32_16x16x32_f16(Ahi, Blo1, acc1, 0, 0, 0);
            acc0 = __builtin_amdgcn_mfma_f32_16x16x32_f16(Alo, Bhi0, acc0, 0, 0, 0);
            acc1 = __builtin_amdgcn_mfma_f32_16x16x32_f16(Alo, Bhi1, acc1, 0, 0, 0);
        }
        __builtin_amdgcn_sched_barrier(0);
        __builtin_amdgcn_s_barrier();   // all waves done reading buf
    }

#pragma unroll
    for (int r = 0; r < 4; r++) {
        size_t rr = (size_t)b * N_ + (n0 + w * 16 + quad * 4 + r);
        aout[rr * H_ + l15]      = acc0[r];
        aout[rr * H_ + 16 + l15] = acc1[r];
    }
}

// ---------------------------------------------------------------- einsum (fallback)
// round-9 version, reads m directly; used only if ws too small
#define CHB 256
__global__ __launch_bounds__(256, 2) void k_einsum_p3(const float* __restrict__ m,
                                                      const _Float16* __restrict__ sT_in_hi,
                                                      const _Float16* __restrict__ sT_in_lo,
                                                      const _Float16* __restrict__ sT_out_hi,
                                                      const _Float16* __restrict__ sT_out_lo,
                                                      float* __restrict__ a_in,
                                                      float* __restrict__ a_out) {
    __shared__ __align__(16) char lds[3 * BUFSZ];
    int bid  = blockIdx.x;
    int xcd  = bid & 7, loc = bid >> 3;
    int pair = xcd * 16 + (loc >> 3);
    int nblk = loc & 7;
    int b    = pair >> 1;
    int dir  = pair & 1;
    int n0   = nblk * 64;
    int tid  = threadIdx.x;
    int w    = tid >> 6;
    int lane = tid & 63;
    int l15  = lane & 15;
    int quad = lane >> 4;

    const char* mBase = (const char*)(m + ((size_t)(b * N_ + n0)) * (2 * KTOT)
                                        + (size_t)dir * KTOT);
    const _Float16* sHi = (dir ? sT_out_hi : sT_in_hi) + (size_t)b * H_ * KTOT;
    const _Float16* sLo = (dir ? sT_out_lo : sT_in_lo) + (size_t)b * H_ * KTOT;
    float* aout = dir ? a_out : a_in;

    int bp   = w >> 1;
    int brb  = (w & 1) << 4;
    const char* sP = (const char*)(bp ? sLo : sHi);

    auto STAGE = [&](int c, int buf) {
        char* dA = lds + buf * BUFSZ;
        char* dB = lds + buf * BUFSZ + BUFA2 + bp * 4096;
#pragma unroll
        for (int i = 0; i < 4; i++) {
            int r = (w << 4) + i * 4 + (lane >> 4);
            const char* g = mBase + (size_t)r * (2 * KTOT * 4) + c * CHB
                            + (((lane & 15) * 16) ^ ((r & 7) << 4));
            gld16(g, dA + ((w << 4) + i * 4) * 256);
        }
#pragma unroll
        for (int i = 0; i < 2; i++) {
            int r = brb + i * 8 + (lane >> 3);
            const char* g = sP + (size_t)r * (KTOT * 2) + c * 128
                            + (((lane & 7) * 16) ^ ((r & 7) << 4));
            gld16(g, dB + (brb + i * 8) * 128);
        }
    };

    f32x4 acc0 = {0.f,0.f,0.f,0.f}, acc1 = {0.f,0.f,0.f,0.f};
    int rowA  = (w << 4) + l15;
    int swzA  = (rowA & 7) << 4;
    int swzB0 = (l15 & 7) << 4;

    STAGE(0, 0);
    STAGE(1, 1);
    for (int c = 0; c < 32; c++) {
        int buf = c % 3;
        if (c + 2 < 32) STAGE(c + 2, (c + 2) % 3);
        if (c + 2 < 32)      asm volatile("s_waitcnt vmcnt(12)" ::: "memory");
        else if (c + 1 < 32) asm volatile("s_waitcnt vmcnt(6)"  ::: "memory");
        else                 asm volatile("s_waitcnt vmcnt(0)"  ::: "memory");
        __builtin_amdgcn_s_barrier();
        __builtin_amdgcn_sched_barrier(0);

        const char* Ab = lds + buf * BUFSZ + rowA * 256;
        const char* Bh = lds + buf * BUFSZ + BUFA2;
        const char* Bl = Bh + 4096;
#pragma unroll
        for (int it = 0; it < 2; it++) {
            int kab = it * 128 + quad * 32;
            f32x4 a0 = *(const f32x4*)(Ab + (kab ^ swzA));
            f32x4 a1 = *(const f32x4*)(Ab + ((kab + 16) ^ swzA));
            int kbb = it * 64 + quad * 16;
            int o0 = l15 * 128        + (kbb ^ swzB0);
            int o1 = (l15 + 16) * 128 + (kbb ^ swzB0);
            half8 Bhi0 = *(const half8*)(Bh + o0);
            half8 Bhi1 = *(const half8*)(Bh + o1);
            half8 Blo0 = *(const half8*)(Bl + o0);
            half8 Blo1 = *(const half8*)(Bl + o1);
            half8 Ahi, Alo;
#pragma unroll
            for (int j = 0; j < 4; j++) {
                float v0 = a0[j], v1 = a1[j];
                _Float16 h0 = (_Float16)v0, h1 = (_Float16)v1;
                Ahi[j] = h0; Ahi[j + 4] = h1;
                Alo[j] = (_Float16)(v0 - (float)h0);
                Alo[j + 4] = (_Float16)(v1 - (float)h1);
            }
            acc0 = __builtin_amdgcn_mfma_f32_16x16x32_f16(Ahi, Bhi0, acc0, 0, 0, 0);
            acc1 = __builtin_amdgcn_mfma_f32_16x16x32_f16(Ahi, Bhi1, acc1, 0, 0, 0);
            acc0 = __builtin_amdgcn_mfma_f32_16x16x32_f16(Ahi, Blo0, acc0, 0, 0, 0);
            acc1 = __builtin_amdgcn_mfma_f32_16x16x32_f16(Ahi, Blo1, acc1, 0, 0, 0);
            acc0 = __builtin_amdgcn_mfma_f32_16x16x32_f16(Alo, Bhi0, acc0, 0, 0, 0);
            acc1 = __builtin_amdgcn_mfma_f32_16x16x32_f16(Alo, Bhi1, acc1, 0, 0, 0);
        }
        __builtin_amdgcn_sched_barrier(0);
        __builtin_amdgcn_s_barrier();
    }
#pragma unroll
    for (int r = 0; r < 4; r++) {
        size_t rr = (size_t)b * N_ + (n0 + w * 16 + quad * 4 + r);
        aout[rr * H_ + l15]      = acc0[r];
        aout[rr * H_ + 16 + l15] = acc1[r];
    }
}

// ---------------------------------------------------------------- GRU gates
// hold comes from hold_src (x at step 0, h afterwards); h written as output
__global__ __launch_bounds__(256) void k_gate(const float* __restrict__ a_in,
                                              const float* __restrict__ a_out,
                                              const float* __restrict__ hold_src,
                                              float* __restrict__ hstate,
                                              const float* __restrict__ Wz,
                                              const float* __restrict__ bz,
                                              const float* __restrict__ Wr,
                                              const float* __restrict__ br,
                                              const float* __restrict__ Wt,
                                              const float* __restrict__ bt) {
    __shared__ float cat[8][96];
    __shared__ float rh[8][32];
    int base = blockIdx.x * 8;     // flattened row b*512+n
    int t = threadIdx.x;

    for (int idx = t; idx < 768; idx += 256) {
        int r = idx / 96, c = idx - r * 96;
        size_t row = (size_t)(base + r);
        float v;
        if (c < 32)      v = a_in [row * 32 + c];
        else if (c < 64) v = a_out[row * 32 + (c - 32)];
        else             v = hold_src[row * 32 + (c - 64)];
        cat[r][c] = v;
    }
    __syncthreads();

    int r = t >> 5, i = t & 31;
    float az = bz[i], ar = br[i];
    const f32x4* wzr = (const f32x4*)(Wz + (size_t)i * 96);
    const f32x4* wrr = (const f32x4*)(Wr + (size_t)i * 96);
    const f32x4* crow = (const f32x4*)cat[r];
#pragma unroll
    for (int kc = 0; kc < 24; kc++) {
        f32x4 cv = crow[kc];
        f32x4 wz = wzr[kc];
        f32x4 wr = wrr[kc];
        az += cv[0]*wz[0] + cv[1]*wz[1] + cv[2]*wz[2] + cv[3]*wz[3];
        ar += cv[0]*wr[0] + cv[1]*wr[1] + cv[2]*wr[2] + cv[3]*wr[3];
    }
    float z  = 1.f / (1.f + __expf(-az));
    float rg = 1.f / (1.f + __expf(-ar));
    float hold = cat[r][64 + i];
    rh[r][i] = rg * hold;
    __syncthreads();

    float at = bt[i];
    const f32x4* wtr = (const f32x4*)(Wt + (size_t)i * 96);
#pragma unroll
    for (int kc = 0; kc < 16; kc++) {
        f32x4 cv = crow[kc];
        f32x4 wt = wtr[kc];
        at += cv[0]*wt[0] + cv[1]*wt[1] + cv[2]*wt[2] + cv[3]*wt[3];
    }
    const f32x4* rrow = (const f32x4*)rh[r];
#pragma unroll
    for (int kc = 0; kc < 8; kc++) {
        f32x4 cv = rrow[kc];
        f32x4 wt = wtr[16 + kc];
        at += cv[0]*wt[0] + cv[1]*wt[1] + cv[2]*wt[2] + cv[3]*wt[3];
    }
    float hh = tanhf(at);
    hstate[(size_t)(base + r) * 32 + i] = (1.f - z) * hold + z * hh;
}

// ---------------------------------------------------------------- readout
__global__ __launch_bounds__(256) void k_final(const float* __restrict__ hstate,
                                               const float* __restrict__ a,
                                               const float* __restrict__ W1,
                                               const float* __restrict__ b1,
                                               const float* __restrict__ W2,
                                               const float* __restrict__ b2,
                                               float* __restrict__ out) {
    __shared__ float hl[8][32];
    __shared__ float as[8];
    int base = blockIdx.x * 8;
    int t = threadIdx.x;
    {
        int r = t >> 5, c = t & 31;
        hl[r][c] = hstate[(size_t)(base + r) * 32 + c];
        if (t < 8) as[t] = a[base + t];
    }
    __syncthreads();
    int r = t >> 5, j = t & 31;
    float acc = b1[j];
    const float* w1r = W1 + (size_t)j * 33;
#pragma unroll
    for (int i2 = 0; i2 < 32; i2++) acc += hl[r][i2] * w1r[i2];
    acc += as[r] * w1r[32];
    float o = tanhf(acc) * W2[j];
#pragma unroll
    for (int off = 16; off; off >>= 1) o += __shfl_xor(o, off, 32);
    if (j == 0) out[base + r] = o + b2[0];
}

// ---------------------------------------------------------------- launcher
extern "C" void kernel_launch(void* const* d_in, const int* in_sizes, int n_in,
                              void* d_out, int out_size, void* d_ws, size_t ws_size,
                              hipStream_t stream) {
    const float* x     = (const float*)d_in[0];
    const float* a     = (const float*)d_in[1];
    const float* m     = (const float*)d_in[2];
    const float* W_in  = (const float*)d_in[3];
    const float* b_in  = (const float*)d_in[4];
    const float* W_out = (const float*)d_in[5];
    const float* b_out = (const float*)d_in[6];
    const float* Wz    = (const float*)d_in[7];
    const float* bz    = (const float*)d_in[8];
    const float* Wr    = (const float*)d_in[9];
    const float* br    = (const float*)d_in[10];
    const float* Wt    = (const float*)d_in[11];
    const float* bt    = (const float*)d_in[12];
    const float* W1    = (const float*)d_in[13];
    const float* b1    = (const float*)d_in[14];
    const float* W2    = (const float*)d_in[15];
    const float* b2    = (const float*)d_in[16];
    float* out = (float*)d_out;

    char* ws = (char*)d_ws;
    float*    h         = (float*)(ws);                           // 4 MB
    float*    a_in      = (float*)(ws + ((size_t)4  << 20));      // 4 MB
    float*    a_out     = (float*)(ws + ((size_t)8  << 20));      // 4 MB
    _Float16* sT_in_hi  = (_Float16*)(ws + ((size_t)12 << 20));   // 8 MB
    _Float16* sT_in_lo  = (_Float16*)(ws + ((size_t)20 << 20));   // 8 MB
    _Float16* sT_out_hi = (_Float16*)(ws + ((size_t)28 << 20));   // 8 MB
    _Float16* sT_out_lo = (_Float16*)(ws + ((size_t)36 << 20));   // 8 MB
    char*     pm        = ws + ((size_t)48 << 20);                // 512 MB (560)

    const int use_pack = (ws_size >= ((size_t)560 << 20));

    if (use_pack)
        k_packm<<<1024, 256, 0, stream>>>(m, pm);

    for (int s = 0; s < NSTEPS; s++) {
        const float* hsrc = (s == 0) ? x : h;
        k_s<<<512, 256, 0, stream>>>(hsrc, W_in, b_in, W_out, b_out,
                                     sT_in_hi, sT_in_lo, sT_out_hi, sT_out_lo);
        if (use_pack)
            k_einsum_pk<<<dim3(8, 64, 2), 256, 0, stream>>>(pm, sT_in_hi, sT_in_lo,
                                                            sT_out_hi, sT_out_lo,
                                                            a_in, a_out);
        else
            k_einsum_p3<<<1024, 256, 0, stream>>>(m, sT_in_hi, sT_in_lo,
                                                  sT_out_hi, sT_out_lo,
                                                  a_in, a_out);
        k_gate<<<4096, 256, 0, stream>>>(a_in, a_out, hsrc, h,
                                         Wz, bz, Wr, br, Wt, bt);
    }
    k_final<<<4096, 256, 0, stream>>>(h, a, W1, b1, W2, b2, out);
}

// Round 14
// 2187.974 us; speedup vs baseline: 1.0931x; 1.0915x over previous
//
#include <hip/hip_runtime.h>
#include <hip/hip_fp16.h>
#include <math.h>

#define B_ 64
#define N_ 512
#define H_ 32
#define E_ 4
#define NSTEPS 5
#define KTOT 2048       // N_*E_

typedef _Float16 half8 __attribute__((ext_vector_type(8)));
typedef float   f32x4 __attribute__((ext_vector_type(4)));

// async global->LDS, 16B per lane; LDS dest = wave-uniform base + lane*16
__device__ __forceinline__ void gld16(const void* g, void* l) {
    __builtin_amdgcn_global_load_lds(
        (const __attribute__((address_space(1))) void*)g,
        (__attribute__((address_space(3))) void*)l, 16, 0, 0);
}

// ---------------------------------------------------------------- fused s+einsum
// block = (nblk, b, dir): 64 output rows, K=2048 in 32 chunks of 64.
// Per chunk c: e = c>>3, n' = (c&7)*64..+63.
//   - m-chunk + h-chunk staged via gld16 (6 linear loads/wave)  [vmcnt only]
//   - VALU phase computes B_c = s(n',he) hi/lo into LDS (k_s's exact math)
//   - PUBLISH: s_waitcnt lgkmcnt(0) BEFORE s_barrier (round-13 bug: raw
//     s_barrier does NOT drain ds_writes -> stale B reads across waves)
//   - B double-buffered (belt & suspenders vs cross-chunk overlap)
//   - MFMA phase consumes A_c x B_c (round-9 body, bit-identical k-order)
#define ABUF 16384      // A: 64 rows x 256B
#define HBUF 8192       // h: 64 rows x 128B
#define BBUF 8192       // B: 2 planes x 32 rows x 128B
__global__ __launch_bounds__(256) void k_es(const float* __restrict__ m,
                                            const float* __restrict__ hsrc,
                                            const float* __restrict__ W_in,
                                            const float* __restrict__ b_in,
                                            const float* __restrict__ W_out,
                                            const float* __restrict__ b_out,
                                            float* __restrict__ a_in,
                                            float* __restrict__ a_out) {
    __shared__ __align__(16) char lds[2 * ABUF + 2 * HBUF + 2 * BBUF]; // 64 KB
    int nblk = blockIdx.x;
    int b    = blockIdx.y;
    int dir  = blockIdx.z;
    int n0   = nblk * 64;
    int tid  = threadIdx.x;
    int w    = tid >> 6;
    int lane = tid & 63;
    int l15  = lane & 15;
    int quad = lane >> 4;
    int hu   = __builtin_amdgcn_readfirstlane(tid >> 6);  // wave-uniform w

    const char* mBase = (const char*)(m + ((size_t)(b * N_ + n0)) * (2 * KTOT)
                                        + (size_t)dir * KTOT);
    const char* hB = (const char*)(hsrc + (size_t)b * N_ * H_);
    const float* Wf  = dir ? W_out : W_in;
    const float* bfp = dir ? b_out : b_in;
    float* aout = dir ? a_out : a_in;

    // stage chunk c: m (4 gld16) + h rows (c&7)*64.. (2 gld16), 6 loads/wave
    auto STAGE = [&](int c, int buf) {
        char* dA = lds + buf * ABUF;
        char* dH = lds + 2 * ABUF + buf * HBUF;
#pragma unroll
        for (int i = 0; i < 4; i++) {                 // A: 4 rows per instr
            int r = (w << 4) + i * 4 + (lane >> 4);
            const char* g = mBase + (size_t)r * (2 * KTOT * 4) + c * 256
                            + (((lane & 15) * 16) ^ ((r & 7) << 4));
            gld16(g, dA + ((w << 4) + i * 4) * 256);
        }
        int hrow0 = (c & 7) * 64;
#pragma unroll
        for (int i = 0; i < 2; i++) {                 // h: 8 rows per instr
            int rl = lane >> 3, pp = lane & 7;
            const char* g = hB + (size_t)(hrow0 + w * 16 + i * 8 + rl) * 128
                            + ((pp ^ (rl & 7)) * 16);
            gld16(g, dH + w * 2048 + i * 1024);
        }
    };

    f32x4 acc0 = {0.f,0.f,0.f,0.f}, acc1 = {0.f,0.f,0.f,0.f};

    int rowA  = (w << 4) + l15;
    int swzA  = (rowA & 7) << 4;
    int swzB0 = (l15 & 7) << 4;       // rows l15 and l15+16 share row&7

    STAGE(0, 0);

    for (int c = 0; c < 32; c++) {
        int buf = c & 1;
        if (c < 31) STAGE(c + 1, buf ^ 1);
        if (c < 31) asm volatile("s_waitcnt vmcnt(6)" ::: "memory");
        else        asm volatile("s_waitcnt vmcnt(0)" ::: "memory");
        __builtin_amdgcn_s_barrier();          // chunk c (m,h) visible
        __builtin_amdgcn_sched_barrier(0);

        char* Bb = lds + 2 * ABUF + 2 * HBUF + buf * BBUF;

        // ---- VALU: compute B_c (s projection, k_s's exact expression tree)
        {
            const char* hC = lds + 2 * ABUF + buf * HBUF;
            int j = lane;                      // n'-row handled by this thread
            f32x4 hv[8];
#pragma unroll
            for (int u = 0; u < 8; u++)
                hv[u] = *(const f32x4*)(hC + j * 128 + ((u ^ (j & 7)) * 16));
            int e = c >> 3;
#pragma unroll
            for (int i = 0; i < 8; i++) {
                int hr = hu * 8 + i;           // output-H row 0..31 (uniform)
                int he = hr * 4 + e;
                const f32x4* wr = (const f32x4*)(Wf + (size_t)he * H_);
                float acc = bfp[he];
#pragma unroll
                for (int c8 = 0; c8 < 8; c8++) {
                    f32x4 wv = wr[c8];
                    acc += hv[c8][0]*wv[0] + hv[c8][1]*wv[1]
                         + hv[c8][2]*wv[2] + hv[c8][3]*wv[3];
                }
                _Float16 hi = (_Float16)acc;
                _Float16 lo = (_Float16)(acc - (float)hi);
                int byte = hr * 128 + ((j * 2) ^ ((hr & 7) << 4));
                *(_Float16*)(Bb + byte)        = hi;
                *(_Float16*)(Bb + 4096 + byte) = lo;
            }
        }
        // PUBLISH B_c: drain ds_writes BEFORE the barrier (round-13 fix)
        asm volatile("s_waitcnt lgkmcnt(0)" ::: "memory");
        __builtin_amdgcn_sched_barrier(0);
        __builtin_amdgcn_s_barrier();          // B_c visible to all waves
        __builtin_amdgcn_sched_barrier(0);

        // ---- MFMA chunk c (round-9 body)
        const char* Ab = lds + buf * ABUF + rowA * 256;
        const char* Bh = Bb;
        const char* Bl = Bb + 4096;
#pragma unroll
        for (int it = 0; it < 2; it++) {
            int kab = it * 128 + quad * 32;          // A byte offset in row
            f32x4 a0 = *(const f32x4*)(Ab + (kab ^ swzA));
            f32x4 a1 = *(const f32x4*)(Ab + ((kab + 16) ^ swzA));

            int kbb = it * 64 + quad * 16;           // B byte offset in row
            int o0 = l15 * 128        + (kbb ^ swzB0);
            int o1 = (l15 + 16) * 128 + (kbb ^ swzB0);
            half8 Bhi0 = *(const half8*)(Bh + o0);
            half8 Bhi1 = *(const half8*)(Bh + o1);
            half8 Blo0 = *(const half8*)(Bl + o0);
            half8 Blo1 = *(const half8*)(Bl + o1);

            half8 Ahi, Alo;
#pragma unroll
            for (int jj = 0; jj < 4; jj++) {
                float v0 = a0[jj], v1 = a1[jj];
                _Float16 h0 = (_Float16)v0, h1 = (_Float16)v1;
                Ahi[jj]     = h0;
                Ahi[jj + 4] = h1;
                Alo[jj]     = (_Float16)(v0 - (float)h0);
                Alo[jj + 4] = (_Float16)(v1 - (float)h1);
            }
            acc0 = __builtin_amdgcn_mfma_f32_16x16x32_f16(Ahi, Bhi0, acc0, 0, 0, 0);
            acc1 = __builtin_amdgcn_mfma_f32_16x16x32_f16(Ahi, Bhi1, acc1, 0, 0, 0);
            acc0 = __builtin_amdgcn_mfma_f32_16x16x32_f16(Ahi, Blo0, acc0, 0, 0, 0);
            acc1 = __builtin_amdgcn_mfma_f32_16x16x32_f16(Ahi, Blo1, acc1, 0, 0, 0);
            acc0 = __builtin_amdgcn_mfma_f32_16x16x32_f16(Alo, Bhi0, acc0, 0, 0, 0);
            acc1 = __builtin_amdgcn_mfma_f32_16x16x32_f16(Alo, Bhi1, acc1, 0, 0, 0);
        }
        // no trailing barrier needed: A/h rows are self-staged/self-read,
        // and B is double-buffered + publish-barrier-protected.
    }

    // D layout: row = quad*4 + r (within 16-row tile), col = l15 (+16 for acc1)
#pragma unroll
    for (int r = 0; r < 4; r++) {
        size_t rr = (size_t)b * N_ + (n0 + w * 16 + quad * 4 + r);
        aout[rr * H_ + l15]      = acc0[r];
        aout[rr * H_ + 16 + l15] = acc1[r];
    }
}

// ---------------------------------------------------------------- GRU gates
// hold comes from hold_src (x at step 0, h afterwards); h written as output
__global__ __launch_bounds__(256) void k_gate(const float* __restrict__ a_in,
                                              const float* __restrict__ a_out,
                                              const float* __restrict__ hold_src,
                                              float* __restrict__ hstate,
                                              const float* __restrict__ Wz,
                                              const float* __restrict__ bz,
                                              const float* __restrict__ Wr,
                                              const float* __restrict__ br,
                                              const float* __restrict__ Wt,
                                              const float* __restrict__ bt) {
    __shared__ float cat[8][96];
    __shared__ float rh[8][32];
    int base = blockIdx.x * 8;     // flattened row b*512+n
    int t = threadIdx.x;

    for (int idx = t; idx < 768; idx += 256) {
        int r = idx / 96, c = idx - r * 96;
        size_t row = (size_t)(base + r);
        float v;
        if (c < 32)      v = a_in [row * 32 + c];
        else if (c < 64) v = a_out[row * 32 + (c - 32)];
        else             v = hold_src[row * 32 + (c - 64)];
        cat[r][c] = v;
    }
    __syncthreads();

    int r = t >> 5, i = t & 31;
    float az = bz[i], ar = br[i];
    const f32x4* wzr = (const f32x4*)(Wz + (size_t)i * 96);
    const f32x4* wrr = (const f32x4*)(Wr + (size_t)i * 96);
    const f32x4* crow = (const f32x4*)cat[r];
#pragma unroll
    for (int kc = 0; kc < 24; kc++) {
        f32x4 cv = crow[kc];
        f32x4 wz = wzr[kc];
        f32x4 wr = wrr[kc];
        az += cv[0]*wz[0] + cv[1]*wz[1] + cv[2]*wz[2] + cv[3]*wz[3];
        ar += cv[0]*wr[0] + cv[1]*wr[1] + cv[2]*wr[2] + cv[3]*wr[3];
    }
    float z  = 1.f / (1.f + __expf(-az));
    float rg = 1.f / (1.f + __expf(-ar));
    float hold = cat[r][64 + i];
    rh[r][i] = rg * hold;
    __syncthreads();

    float at = bt[i];
    const f32x4* wtr = (const f32x4*)(Wt + (size_t)i * 96);
#pragma unroll
    for (int kc = 0; kc < 16; kc++) {     // a_in | a_out part
        f32x4 cv = crow[kc];
        f32x4 wt = wtr[kc];
        at += cv[0]*wt[0] + cv[1]*wt[1] + cv[2]*wt[2] + cv[3]*wt[3];
    }
    const f32x4* rrow = (const f32x4*)rh[r];
#pragma unroll
    for (int kc = 0; kc < 8; kc++) {      // r*h part
        f32x4 cv = rrow[kc];
        f32x4 wt = wtr[16 + kc];
        at += cv[0]*wt[0] + cv[1]*wt[1] + cv[2]*wt[2] + cv[3]*wt[3];
    }
    float hh = tanhf(at);
    hstate[(size_t)(base + r) * 32 + i] = (1.f - z) * hold + z * hh;
}

// ---------------------------------------------------------------- readout
__global__ __launch_bounds__(256) void k_final(const float* __restrict__ hstate,
                                               const float* __restrict__ a,
                                               const float* __restrict__ W1,
                                               const float* __restrict__ b1,
                                               const float* __restrict__ W2,
                                               const float* __restrict__ b2,
                                               float* __restrict__ out) {
    __shared__ float hl[8][32];
    __shared__ float as[8];
    int base = blockIdx.x * 8;
    int t = threadIdx.x;
    {
        int r = t >> 5, c = t & 31;
        hl[r][c] = hstate[(size_t)(base + r) * 32 + c];
        if (t < 8) as[t] = a[base + t];
    }
    __syncthreads();
    int r = t >> 5, j = t & 31;
    float acc = b1[j];
    const float* w1r = W1 + (size_t)j * 33;
#pragma unroll
    for (int i2 = 0; i2 < 32; i2++) acc += hl[r][i2] * w1r[i2];
    acc += as[r] * w1r[32];
    float o = tanhf(acc) * W2[j];
#pragma unroll
    for (int off = 16; off; off >>= 1) o += __shfl_xor(o, off, 32);
    if (j == 0) out[base + r] = o + b2[0];
}

// ---------------------------------------------------------------- launcher
extern "C" void kernel_launch(void* const* d_in, const int* in_sizes, int n_in,
                              void* d_out, int out_size, void* d_ws, size_t ws_size,
                              hipStream_t stream) {
    const float* x     = (const float*)d_in[0];
    const float* a     = (const float*)d_in[1];
    const float* m     = (const float*)d_in[2];
    const float* W_in  = (const float*)d_in[3];
    const float* b_in  = (const float*)d_in[4];
    const float* W_out = (const float*)d_in[5];
    const float* b_out = (const float*)d_in[6];
    const float* Wz    = (const float*)d_in[7];
    const float* bz    = (const float*)d_in[8];
    const float* Wr    = (const float*)d_in[9];
    const float* br    = (const float*)d_in[10];
    const float* Wt    = (const float*)d_in[11];
    const float* bt    = (const float*)d_in[12];
    const float* W1    = (const float*)d_in[13];
    const float* b1    = (const float*)d_in[14];
    const float* W2    = (const float*)d_in[15];
    const float* b2    = (const float*)d_in[16];
    float* out = (float*)d_out;

    char* ws = (char*)d_ws;
    float* h    = (float*)(ws);                        // 4 MB
    float* a_in = (float*)(ws + ((size_t)4 << 20));    // 4 MB
    float* a_out= (float*)(ws + ((size_t)8 << 20));    // 4 MB (12 MB total)

    for (int s = 0; s < NSTEPS; s++) {
        const float* hsrc = (s == 0) ? x : h;
        k_es<<<dim3(8, 64, 2), 256, 0, stream>>>(m, hsrc, W_in, b_in,
                                                 W_out, b_out, a_in, a_out);
        k_gate<<<4096, 256, 0, stream>>>(a_in, a_out, hsrc, h,
                                         Wz, bz, Wr, br, Wt, bt);
    }
    k_final<<<4096, 256, 0, stream>>>(h, a, W1, b1, W2, b2, out);
}

// Round 15
// 2143.785 us; speedup vs baseline: 1.1156x; 1.0206x over previous
//
#include <hip/hip_runtime.h>
#include <hip/hip_fp16.h>
#include <math.h>

#define B_ 64
#define N_ 512
#define H_ 32
#define E_ 4
#define NSTEPS 5
#define KTOT 2048       // N_*E_

typedef _Float16 half8 __attribute__((ext_vector_type(8)));
typedef float   f32x4 __attribute__((ext_vector_type(4)));

// async global->LDS, 16B per lane; LDS dest = wave-uniform base + lane*16
__device__ __forceinline__ void gld16(const void* g, void* l) {
    __builtin_amdgcn_global_load_lds(
        (const __attribute__((address_space(1))) void*)g,
        (__attribute__((address_space(3))) void*)l, 16, 0, 0);
}

// ---------------------------------------------------------------- fused s+einsum
// block -> tile (nblk, b, dir) via flat id; on odd steps the mapping is
// REVERSED (flat -> 1023-flat) so the step's traversal starts where the
// previous step's ended -> the ~256MB L3 tail of step s is the head of step
// s+1 (alternating-direction L3 reuse; bit-exact permutation, math unchanged).
// Per chunk c: e = c>>3, n' = (c&7)*64..+63.
//   - m-chunk + h-chunk staged via gld16 (6 linear loads/wave)  [vmcnt only]
//   - VALU phase computes B_c = s(n',he) hi/lo into LDS (k_s's exact math)
//   - PUBLISH: s_waitcnt lgkmcnt(0) BEFORE s_barrier (round-13 lesson)
//   - B double-buffered; MFMA phase = round-9 body, bit-identical k-order
#define ABUF 16384      // A: 64 rows x 256B
#define HBUF 8192       // h: 64 rows x 128B
#define BBUF 8192       // B: 2 planes x 32 rows x 128B
__global__ __launch_bounds__(256) void k_es(const float* __restrict__ m,
                                            const float* __restrict__ hsrc,
                                            const float* __restrict__ W_in,
                                            const float* __restrict__ b_in,
                                            const float* __restrict__ W_out,
                                            const float* __restrict__ b_out,
                                            float* __restrict__ a_in,
                                            float* __restrict__ a_out,
                                            int rev) {
    __shared__ __align__(16) char lds[2 * ABUF + 2 * HBUF + 2 * BBUF]; // 64 KB
    int flat = blockIdx.x + (blockIdx.y << 3) + (blockIdx.z << 9);  // 0..1023
    if (rev) flat = 1023 - flat;
    int nblk = flat & 7;
    int b    = (flat >> 3) & 63;
    int dir  = flat >> 9;
    int n0   = nblk * 64;
    int tid  = threadIdx.x;
    int w    = tid >> 6;
    int lane = tid & 63;
    int l15  = lane & 15;
    int quad = lane >> 4;
    int hu   = __builtin_amdgcn_readfirstlane(tid >> 6);  // wave-uniform w

    const char* mBase = (const char*)(m + ((size_t)(b * N_ + n0)) * (2 * KTOT)
                                        + (size_t)dir * KTOT);
    const char* hB = (const char*)(hsrc + (size_t)b * N_ * H_);
    const float* Wf  = dir ? W_out : W_in;
    const float* bfp = dir ? b_out : b_in;
    float* aout = dir ? a_out : a_in;

    // stage chunk c: m (4 gld16) + h rows (c&7)*64.. (2 gld16), 6 loads/wave
    auto STAGE = [&](int c, int buf) {
        char* dA = lds + buf * ABUF;
        char* dH = lds + 2 * ABUF + buf * HBUF;
#pragma unroll
        for (int i = 0; i < 4; i++) {                 // A: 4 rows per instr
            int r = (w << 4) + i * 4 + (lane >> 4);
            const char* g = mBase + (size_t)r * (2 * KTOT * 4) + c * 256
                            + (((lane & 15) * 16) ^ ((r & 7) << 4));
            gld16(g, dA + ((w << 4) + i * 4) * 256);
        }
        int hrow0 = (c & 7) * 64;
#pragma unroll
        for (int i = 0; i < 2; i++) {                 // h: 8 rows per instr
            int rl = lane >> 3, pp = lane & 7;
            const char* g = hB + (size_t)(hrow0 + w * 16 + i * 8 + rl) * 128
                            + ((pp ^ (rl & 7)) * 16);
            gld16(g, dH + w * 2048 + i * 1024);
        }
    };

    f32x4 acc0 = {0.f,0.f,0.f,0.f}, acc1 = {0.f,0.f,0.f,0.f};

    int rowA  = (w << 4) + l15;
    int swzA  = (rowA & 7) << 4;
    int swzB0 = (l15 & 7) << 4;       // rows l15 and l15+16 share row&7

    STAGE(0, 0);

    for (int c = 0; c < 32; c++) {
        int buf = c & 1;
        if (c < 31) STAGE(c + 1, buf ^ 1);
        if (c < 31) asm volatile("s_waitcnt vmcnt(6)" ::: "memory");
        else        asm volatile("s_waitcnt vmcnt(0)" ::: "memory");
        __builtin_amdgcn_s_barrier();          // chunk c (m,h) visible
        __builtin_amdgcn_sched_barrier(0);

        char* Bb = lds + 2 * ABUF + 2 * HBUF + buf * BBUF;

        // ---- VALU: compute B_c (s projection, k_s's exact expression tree)
        {
            const char* hC = lds + 2 * ABUF + buf * HBUF;
            int j = lane;                      // n'-row handled by this thread
            f32x4 hv[8];
#pragma unroll
            for (int u = 0; u < 8; u++)
                hv[u] = *(const f32x4*)(hC + j * 128 + ((u ^ (j & 7)) * 16));
            int e = c >> 3;
#pragma unroll
            for (int i = 0; i < 8; i++) {
                int hr = hu * 8 + i;           // output-H row 0..31 (uniform)
                int he = hr * 4 + e;
                const f32x4* wr = (const f32x4*)(Wf + (size_t)he * H_);
                float acc = bfp[he];
#pragma unroll
                for (int c8 = 0; c8 < 8; c8++) {
                    f32x4 wv = wr[c8];
                    acc += hv[c8][0]*wv[0] + hv[c8][1]*wv[1]
                         + hv[c8][2]*wv[2] + hv[c8][3]*wv[3];
                }
                _Float16 hi = (_Float16)acc;
                _Float16 lo = (_Float16)(acc - (float)hi);
                int byte = hr * 128 + ((j * 2) ^ ((hr & 7) << 4));
                *(_Float16*)(Bb + byte)        = hi;
                *(_Float16*)(Bb + 4096 + byte) = lo;
            }
        }
        // PUBLISH B_c: drain ds_writes BEFORE the barrier
        asm volatile("s_waitcnt lgkmcnt(0)" ::: "memory");
        __builtin_amdgcn_sched_barrier(0);
        __builtin_amdgcn_s_barrier();          // B_c visible to all waves
        __builtin_amdgcn_sched_barrier(0);

        // ---- MFMA chunk c (round-9 body)
        const char* Ab = lds + buf * ABUF + rowA * 256;
        const char* Bh = Bb;
        const char* Bl = Bb + 4096;
#pragma unroll
        for (int it = 0; it < 2; it++) {
            int kab = it * 128 + quad * 32;          // A byte offset in row
            f32x4 a0 = *(const f32x4*)(Ab + (kab ^ swzA));
            f32x4 a1 = *(const f32x4*)(Ab + ((kab + 16) ^ swzA));

            int kbb = it * 64 + quad * 16;           // B byte offset in row
            int o0 = l15 * 128        + (kbb ^ swzB0);
            int o1 = (l15 + 16) * 128 + (kbb ^ swzB0);
            half8 Bhi0 = *(const half8*)(Bh + o0);
            half8 Bhi1 = *(const half8*)(Bh + o1);
            half8 Blo0 = *(const half8*)(Bl + o0);
            half8 Blo1 = *(const half8*)(Bl + o1);

            half8 Ahi, Alo;
#pragma unroll
            for (int jj = 0; jj < 4; jj++) {
                float v0 = a0[jj], v1 = a1[jj];
                _Float16 h0 = (_Float16)v0, h1 = (_Float16)v1;
                Ahi[jj]     = h0;
                Ahi[jj + 4] = h1;
                Alo[jj]     = (_Float16)(v0 - (float)h0);
                Alo[jj + 4] = (_Float16)(v1 - (float)h1);
            }
            acc0 = __builtin_amdgcn_mfma_f32_16x16x32_f16(Ahi, Bhi0, acc0, 0, 0, 0);
            acc1 = __builtin_amdgcn_mfma_f32_16x16x32_f16(Ahi, Bhi1, acc1, 0, 0, 0);
            acc0 = __builtin_amdgcn_mfma_f32_16x16x32_f16(Ahi, Blo0, acc0, 0, 0, 0);
            acc1 = __builtin_amdgcn_mfma_f32_16x16x32_f16(Ahi, Blo1, acc1, 0, 0, 0);
            acc0 = __builtin_amdgcn_mfma_f32_16x16x32_f16(Alo, Bhi0, acc0, 0, 0, 0);
            acc1 = __builtin_amdgcn_mfma_f32_16x16x32_f16(Alo, Bhi1, acc1, 0, 0, 0);
        }
        // no trailing barrier needed: A/h rows are self-staged/self-read,
        // and B is double-buffered + publish-barrier-protected.
    }

    // D layout: row = quad*4 + r (within 16-row tile), col = l15 (+16 for acc1)
#pragma unroll
    for (int r = 0; r < 4; r++) {
        size_t rr = (size_t)b * N_ + (n0 + w * 16 + quad * 4 + r);
        aout[rr * H_ + l15]      = acc0[r];
        aout[rr * H_ + 16 + l15] = acc1[r];
    }
}

// ---------------------------------------------------------------- GRU gates
// hold comes from hold_src (x at step 0, h afterwards); h written as output
__global__ __launch_bounds__(256) void k_gate(const float* __restrict__ a_in,
                                              const float* __restrict__ a_out,
                                              const float* __restrict__ hold_src,
                                              float* __restrict__ hstate,
                                              const float* __restrict__ Wz,
                                              const float* __restrict__ bz,
                                              const float* __restrict__ Wr,
                                              const float* __restrict__ br,
                                              const float* __restrict__ Wt,
                                              const float* __restrict__ bt) {
    __shared__ float cat[8][96];
    __shared__ float rh[8][32];
    int base = blockIdx.x * 8;     // flattened row b*512+n
    int t = threadIdx.x;

    for (int idx = t; idx < 768; idx += 256) {
        int r = idx / 96, c = idx - r * 96;
        size_t row = (size_t)(base + r);
        float v;
        if (c < 32)      v = a_in [row * 32 + c];
        else if (c < 64) v = a_out[row * 32 + (c - 32)];
        else             v = hold_src[row * 32 + (c - 64)];
        cat[r][c] = v;
    }
    __syncthreads();

    int r = t >> 5, i = t & 31;
    float az = bz[i], ar = br[i];
    const f32x4* wzr = (const f32x4*)(Wz + (size_t)i * 96);
    const f32x4* wrr = (const f32x4*)(Wr + (size_t)i * 96);
    const f32x4* crow = (const f32x4*)cat[r];
#pragma unroll
    for (int kc = 0; kc < 24; kc++) {
        f32x4 cv = crow[kc];
        f32x4 wz = wzr[kc];
        f32x4 wr = wrr[kc];
        az += cv[0]*wz[0] + cv[1]*wz[1] + cv[2]*wz[2] + cv[3]*wz[3];
        ar += cv[0]*wr[0] + cv[1]*wr[1] + cv[2]*wr[2] + cv[3]*wr[3];
    }
    float z  = 1.f / (1.f + __expf(-az));
    float rg = 1.f / (1.f + __expf(-ar));
    float hold = cat[r][64 + i];
    rh[r][i] = rg * hold;
    __syncthreads();

    float at = bt[i];
    const f32x4* wtr = (const f32x4*)(Wt + (size_t)i * 96);
#pragma unroll
    for (int kc = 0; kc < 16; kc++) {     // a_in | a_out part
        f32x4 cv = crow[kc];
        f32x4 wt = wtr[kc];
        at += cv[0]*wt[0] + cv[1]*wt[1] + cv[2]*wt[2] + cv[3]*wt[3];
    }
    const f32x4* rrow = (const f32x4*)rh[r];
#pragma unroll
    for (int kc = 0; kc < 8; kc++) {      // r*h part
        f32x4 cv = rrow[kc];
        f32x4 wt = wtr[16 + kc];
        at += cv[0]*wt[0] + cv[1]*wt[1] + cv[2]*wt[2] + cv[3]*wt[3];
    }
    float hh = tanhf(at);
    hstate[(size_t)(base + r) * 32 + i] = (1.f - z) * hold + z * hh;
}

// ---------------------------------------------------------------- readout
__global__ __launch_bounds__(256) void k_final(const float* __restrict__ hstate,
                                               const float* __restrict__ a,
                                               const float* __restrict__ W1,
                                               const float* __restrict__ b1,
                                               const float* __restrict__ W2,
                                               const float* __restrict__ b2,
                                               float* __restrict__ out) {
    __shared__ float hl[8][32];
    __shared__ float as[8];
    int base = blockIdx.x * 8;
    int t = threadIdx.x;
    {
        int r = t >> 5, c = t & 31;
        hl[r][c] = hstate[(size_t)(base + r) * 32 + c];
        if (t < 8) as[t] = a[base + t];
    }
    __syncthreads();
    int r = t >> 5, j = t & 31;
    float acc = b1[j];
    const float* w1r = W1 + (size_t)j * 33;
#pragma unroll
    for (int i2 = 0; i2 < 32; i2++) acc += hl[r][i2] * w1r[i2];
    acc += as[r] * w1r[32];
    float o = tanhf(acc) * W2[j];
#pragma unroll
    for (int off = 16; off; off >>= 1) o += __shfl_xor(o, off, 32);
    if (j == 0) out[base + r] = o + b2[0];
}

// ---------------------------------------------------------------- launcher
extern "C" void kernel_launch(void* const* d_in, const int* in_sizes, int n_in,
                              void* d_out, int out_size, void* d_ws, size_t ws_size,
                              hipStream_t stream) {
    const float* x     = (const float*)d_in[0];
    const float* a     = (const float*)d_in[1];
    const float* m     = (const float*)d_in[2];
    const float* W_in  = (const float*)d_in[3];
    const float* b_in  = (const float*)d_in[4];
    const float* W_out = (const float*)d_in[5];
    const float* b_out = (const float*)d_in[6];
    const float* Wz    = (const float*)d_in[7];
    const float* bz    = (const float*)d_in[8];
    const float* Wr    = (const float*)d_in[9];
    const float* br    = (const float*)d_in[10];
    const float* Wt    = (const float*)d_in[11];
    const float* bt    = (const float*)d_in[12];
    const float* W1    = (const float*)d_in[13];
    const float* b1    = (const float*)d_in[14];
    const float* W2    = (const float*)d_in[15];
    const float* b2    = (const float*)d_in[16];
    float* out = (float*)d_out;

    char* ws = (char*)d_ws;
    float* h    = (float*)(ws);                        // 4 MB
    float* a_in = (float*)(ws + ((size_t)4 << 20));    // 4 MB
    float* a_out= (float*)(ws + ((size_t)8 << 20));    // 4 MB (12 MB total)

    for (int s = 0; s < NSTEPS; s++) {
        const float* hsrc = (s == 0) ? x : h;
        k_es<<<dim3(8, 64, 2), 256, 0, stream>>>(m, hsrc, W_in, b_in,
                                                 W_out, b_out, a_in, a_out,
                                                 s & 1);
        k_gate<<<4096, 256, 0, stream>>>(a_in, a_out, hsrc, h,
                                         Wz, bz, Wr, br, Wt, bt);
    }
    k_final<<<4096, 256, 0, stream>>>(h, a, W1, b1, W2, b2, out);
}